// Round 9
// baseline (2174.055 us; speedup 1.0000x reference)
//
#include <hip/hip_runtime.h>
#include <math.h>

// ---------------- constants ----------------
#define INTER 128
#define OUTD  64
#define SCAN_T 256
#define SCAN_E 1024
#define NSLOT 64     // graph-sum contention-spreading slots
#define NBIN  128    // degree bins for counting sort

using bf16x8 = __attribute__((ext_vector_type(8))) short;
using f32x4  = __attribute__((ext_vector_type(4))) float;

static __device__ __forceinline__ unsigned short f2bf(float f) {
    unsigned int u = __float_as_uint(f);
    u += 0x7fffu + ((u >> 16) & 1u);          // RTNE
    return (unsigned short)(u >> 16);
}
static __device__ __forceinline__ unsigned int pk2(float a, float b) {
    return (unsigned int)f2bf(a) | ((unsigned int)f2bf(b) << 16);
}
static __device__ __forceinline__ float bflo(unsigned int u) { return __uint_as_float(u << 16); }
static __device__ __forceinline__ float bfhi(unsigned int u) { return __uint_as_float(u & 0xffff0000u); }

static __device__ __forceinline__ void fma8(float* a, float w, uint4 v) {
    a[0] = fmaf(w, bflo(v.x), a[0]); a[1] = fmaf(w, bfhi(v.x), a[1]);
    a[2] = fmaf(w, bflo(v.y), a[2]); a[3] = fmaf(w, bfhi(v.y), a[3]);
    a[4] = fmaf(w, bflo(v.z), a[4]); a[5] = fmaf(w, bfhi(v.z), a[5]);
    a[6] = fmaf(w, bflo(v.w), a[6]); a[7] = fmaf(w, bfhi(v.w), a[7]);
}
static __device__ __forceinline__ void seed8(float* a, float sn, uint4 v) {
    a[0] = sn * bflo(v.x); a[1] = sn * bfhi(v.x);
    a[2] = sn * bflo(v.y); a[3] = sn * bfhi(v.y);
    a[4] = sn * bflo(v.z); a[5] = sn * bfhi(v.z);
    a[6] = sn * bflo(v.w); a[7] = sn * bfhi(v.w);
}

// ---------------- CSR build ----------------
__global__ void count_k(const int* __restrict__ dst, int* __restrict__ cnt, int E) {
    int e = blockIdx.x * 256 + threadIdx.x;
    if (e < E) atomicAdd(&cnt[dst[e]], 1);
}

__global__ void dinv_k(const int* __restrict__ cnt, float* __restrict__ dinv, int N) {
    int i = blockIdx.x * 256 + threadIdx.x;
    if (i < N) dinv[i] = rsqrtf((float)(cnt[i] + 1));
}

__global__ void scan_block(const int* __restrict__ in, int* __restrict__ out,
                           int* __restrict__ bsums, int n) {
    __shared__ int sh[SCAN_T];
    int base = blockIdx.x * SCAN_E;
    int t = threadIdx.x;
    int v[4];
    int s = 0;
#pragma unroll
    for (int i = 0; i < 4; i++) {
        int idx = base + t * 4 + i;
        v[i] = (idx < n) ? in[idx] : 0;
        s += v[i];
    }
    sh[t] = s;
    __syncthreads();
    for (int off = 1; off < SCAN_T; off <<= 1) {
        int x = (t >= off) ? sh[t - off] : 0;
        __syncthreads();
        sh[t] += x;
        __syncthreads();
    }
    int excl = (t == 0) ? 0 : sh[t - 1];
    if (bsums && t == SCAN_T - 1) bsums[blockIdx.x] = sh[t];
#pragma unroll
    for (int i = 0; i < 4; i++) {
        int idx = base + t * 4 + i;
        if (idx < n) out[idx] = excl;
        excl += v[i];
    }
}

__global__ void scan_add(int* __restrict__ out, const int* __restrict__ bsums, int n, int total) {
    int idx = blockIdx.x * SCAN_E + threadIdx.x * 4;
    int add = bsums[blockIdx.x];
#pragma unroll
    for (int i = 0; i < 4; i++) {
        int j = idx + i;
        if (j < n) out[j] += add;
    }
    if (blockIdx.x == 0 && threadIdx.x == 0) out[n] = total;
}

__global__ void scatter_k(const int* __restrict__ src, const int* __restrict__ dst,
                          const int* __restrict__ rs, int* __restrict__ cursor,
                          const float* __restrict__ dinv,
                          int2* __restrict__ cw, int E) {
    int e = blockIdx.x * 256 + threadIdx.x;
    if (e >= E) return;
    int s = src[e], d = dst[e];
    int pos = rs[d] + atomicAdd(&cursor[d], 1);
    cw[pos] = make_int2(s, __float_as_int(dinv[s] * dinv[d]));
}

// ---------------- degree counting sort (node order for load-balanced blocks) ----
__global__ void dhist_k(const int* __restrict__ cnt, int* __restrict__ hist, int N) {
    int i = blockIdx.x * 256 + threadIdx.x;
    if (i < N) atomicAdd(&hist[min(cnt[i], NBIN - 1)], 1);
}

__global__ void dscan_k(const int* __restrict__ hist, int* __restrict__ bincur) {
    if (threadIdx.x == 0) {
        int s = 0;
        for (int b = 0; b < NBIN; b++) { bincur[b] = s; s += hist[b]; }
    }
}

__global__ void dorder_k(const int* __restrict__ cnt, int* __restrict__ bincur,
                         int* __restrict__ order, int N) {
    int i = blockIdx.x * 256 + threadIdx.x;
    if (i >= N) return;
    int d = min(cnt[i], NBIN - 1);
    int p = atomicAdd(&bincur[d], 1);
    order[p] = i;
}

// ---------------- weight prep (fp32 -> bf16, transposed [n][k]) ----------------
__global__ void wprep_h(const float* __restrict__ W, unsigned short* __restrict__ Wt, int L) {
    int tid = blockIdx.x * 256 + threadIdx.x;
    if (tid >= L * INTER * INTER) return;
    int l = tid / (INTER * INTER);
    int r = tid % (INTER * INTER);
    int n = r / INTER, k = r % INTER;
    Wt[tid] = f2bf(W[(size_t)l * INTER * INTER + (size_t)k * INTER + n]);
}

__global__ void wprep_o(const float* __restrict__ W, unsigned short* __restrict__ Wt) {
    int tid = blockIdx.x * 256 + threadIdx.x;
    if (tid >= OUTD * INTER) return;
    int n = tid / INTER, k = tid % INTER;
    Wt[tid] = f2bf(W[(size_t)k * OUTD + n]);
}

// ---------------- input layer ----------------
__global__ void agg2(const float* __restrict__ x, const int* __restrict__ rs,
                     const int2* __restrict__ cw, const float* __restrict__ dinv,
                     float* __restrict__ ax, int N) {
    int i = blockIdx.x * 256 + threadIdx.x;
    if (i >= N) return;
    float di = dinv[i];
    float sn = di * di;
    float2 xv = ((const float2*)x)[i];
    float a0 = sn * xv.x, a1 = sn * xv.y;
    int e0 = rs[i], e1 = rs[i + 1];
    for (int k = e0; k < e1; k++) {
        int2 c = cw[k];
        float wk = __int_as_float(c.y);
        float2 xs = ((const float2*)x)[c.x];
        a0 += wk * xs.x;
        a1 += wk * xs.y;
    }
    ((float2*)ax)[i] = make_float2(a0, a1);
}

// h = ax (N x 2) @ W_in (2 x 128) + b_in  -> bf16
__global__ void gemm_in(const float* __restrict__ ax, const float* __restrict__ Wi,
                        const float* __restrict__ bi, unsigned short* __restrict__ h, int N) {
    int node = blockIdx.x * 2 + threadIdx.x / 128;
    int j = threadIdx.x % 128;
    if (node >= N) return;
    float2 a = ((const float2*)ax)[node];
    h[(size_t)node * 128 + j] = f2bf(fmaf(a.x, Wi[j], fmaf(a.y, Wi[128 + j], bi[j])));
}

// ---------------- fused hidden layer: Hout = relu((A_hat Hin) W + b) ----------------
// Nodes processed in degree-sorted order (order[]), so each block's 32 nodes have
// ~equal degree -> no serialization on the block barrier.
// Phase 1: dual-node, quad-edge CSR gather (8 loads in flight) -> bf16 LDS T[32][136].
// Phase 2: wave wv owns cols [wv*32,(wv+1)*32) x both node chunks; Wt read once/block.
__global__ __launch_bounds__(256) void fused_hidden4(
    const unsigned short* __restrict__ Hin,
    const int* __restrict__ rs, const int2* __restrict__ cw,
    const float* __restrict__ dinv, const int* __restrict__ order,
    const unsigned short* __restrict__ Wt,   // [128][128] bf16, Wt[n][k] = W[k][n]
    const float* __restrict__ bias,
    unsigned short* __restrict__ Hout, int N)
{
    __shared__ __align__(16) unsigned short T[32][136];
    __shared__ int nodeid[32];
    const int t = threadIdx.x;
    const int q = t & 15;        // 16 lanes per node
    const int gi = t >> 4;       // 0..15
    const int sA = blockIdx.x * 32 + gi;
    const int sB = sA + 16;
    const bool vA = sA < N, vB = sB < N;
    const int nA = vA ? order[sA] : 0;
    const int nB = vB ? order[sB] : 0;
    if (q == 0) {
        nodeid[gi]      = vA ? nA : -1;
        nodeid[gi + 16] = vB ? nB : -1;
    }

    float accA[8] = {0,0,0,0,0,0,0,0}, accB[8] = {0,0,0,0,0,0,0,0};
    if (vA) {
        float dA = dinv[nA];
        seed8(accA, dA * dA, *(const uint4*)(Hin + (size_t)nA * 128 + q * 8));
    }
    if (vB) {
        float dB = dinv[nB];
        seed8(accB, dB * dB, *(const uint4*)(Hin + (size_t)nB * 128 + q * 8));
    }
    int kA = 0, eA = 0, kB = 0, eB = 0;
    if (vA) { kA = rs[nA]; eA = rs[nA + 1]; }
    if (vB) { kB = rs[nB]; eB = rs[nB + 1]; }

    while (kA < eA || kB < eB) {
        int2 cA0 = (kA     < eA) ? cw[kA]     : make_int2(0, 0);
        int2 cA1 = (kA + 1 < eA) ? cw[kA + 1] : make_int2(0, 0);
        int2 cA2 = (kA + 2 < eA) ? cw[kA + 2] : make_int2(0, 0);
        int2 cA3 = (kA + 3 < eA) ? cw[kA + 3] : make_int2(0, 0);
        int2 cB0 = (kB     < eB) ? cw[kB]     : make_int2(0, 0);
        int2 cB1 = (kB + 1 < eB) ? cw[kB + 1] : make_int2(0, 0);
        int2 cB2 = (kB + 2 < eB) ? cw[kB + 2] : make_int2(0, 0);
        int2 cB3 = (kB + 3 < eB) ? cw[kB + 3] : make_int2(0, 0);
        uint4 vA0 = *(const uint4*)(Hin + (size_t)cA0.x * 128 + q * 8);
        uint4 vA1 = *(const uint4*)(Hin + (size_t)cA1.x * 128 + q * 8);
        uint4 vA2 = *(const uint4*)(Hin + (size_t)cA2.x * 128 + q * 8);
        uint4 vA3 = *(const uint4*)(Hin + (size_t)cA3.x * 128 + q * 8);
        uint4 vB0 = *(const uint4*)(Hin + (size_t)cB0.x * 128 + q * 8);
        uint4 vB1 = *(const uint4*)(Hin + (size_t)cB1.x * 128 + q * 8);
        uint4 vB2 = *(const uint4*)(Hin + (size_t)cB2.x * 128 + q * 8);
        uint4 vB3 = *(const uint4*)(Hin + (size_t)cB3.x * 128 + q * 8);
        fma8(accA, __int_as_float(cA0.y), vA0);
        fma8(accA, __int_as_float(cA1.y), vA1);
        fma8(accA, __int_as_float(cA2.y), vA2);
        fma8(accA, __int_as_float(cA3.y), vA3);
        fma8(accB, __int_as_float(cB0.y), vB0);
        fma8(accB, __int_as_float(cB1.y), vB1);
        fma8(accB, __int_as_float(cB2.y), vB2);
        fma8(accB, __int_as_float(cB3.y), vB3);
        kA += 4; kB += 4;
    }

    {
        uint4 oA = make_uint4(pk2(accA[0], accA[1]), pk2(accA[2], accA[3]),
                              pk2(accA[4], accA[5]), pk2(accA[6], accA[7]));
        uint4 oB = make_uint4(pk2(accB[0], accB[1]), pk2(accB[2], accB[3]),
                              pk2(accB[4], accB[5]), pk2(accB[6], accB[7]));
        *(uint4*)&T[gi][q * 8] = oA;
        *(uint4*)&T[gi + 16][q * 8] = oB;
    }
    __syncthreads();

    // phase 2
    const int wv = t >> 6;       // wave -> col slice [wv*32, wv*32+32)
    const int lane = t & 63;
    const int r15 = lane & 15;
    const int kg = lane >> 4;

    bf16x8 bfr[2][4];
#pragma unroll
    for (int nc = 0; nc < 2; nc++)
#pragma unroll
        for (int ks = 0; ks < 4; ks++)
            bfr[nc][ks] = *(const bf16x8*)&T[nc * 16 + r15][kg * 8 + ks * 32];

    f32x4 acc[2][2];
#pragma unroll
    for (int nc = 0; nc < 2; nc++)
#pragma unroll
        for (int c = 0; c < 2; c++) acc[nc][c] = (f32x4){0.f, 0.f, 0.f, 0.f};

#pragma unroll
    for (int c = 0; c < 2; c++) {
        const unsigned short* wrow = Wt + (size_t)(wv * 32 + c * 16 + r15) * 128 + kg * 8;
#pragma unroll
        for (int ks = 0; ks < 4; ks++) {
            bf16x8 afr = *(const bf16x8*)(wrow + ks * 32);
            acc[0][c] = __builtin_amdgcn_mfma_f32_16x16x32_bf16(afr, bfr[0][ks], acc[0][c], 0, 0, 0);
            acc[1][c] = __builtin_amdgcn_mfma_f32_16x16x32_bf16(afr, bfr[1][ks], acc[1][c], 0, 0, 0);
        }
    }

#pragma unroll
    for (int nc = 0; nc < 2; nc++) {
        const int node = nodeid[nc * 16 + r15];
        if (node >= 0) {
#pragma unroll
            for (int c = 0; c < 2; c++) {
                int col = wv * 32 + c * 16 + kg * 4;
                float4 bv = *(const float4*)(bias + col);
                float v0 = fmaxf(acc[nc][c][0] + bv.x, 0.f);
                float v1 = fmaxf(acc[nc][c][1] + bv.y, 0.f);
                float v2 = fmaxf(acc[nc][c][2] + bv.z, 0.f);
                float v3 = fmaxf(acc[nc][c][3] + bv.w, 0.f);
                *(uint2*)(Hout + (size_t)node * 128 + col) = make_uint2(pk2(v0, v1), pk2(v2, v3));
            }
        }
    }
}

// ---------------- output transform: g = Hin (N x 128) @ W_out (128 x 64) -> bf16 ----------------
__global__ __launch_bounds__(256) void gemm_out(const unsigned short* __restrict__ Hin,
                                                const unsigned short* __restrict__ Wt, // [64][128]
                                                unsigned short* __restrict__ g, int N) {
    const int wv = threadIdx.x >> 6;
    const int lane = threadIdx.x & 63;
    const int r15 = lane & 15;
    const int kg = lane >> 4;
    const int node0 = blockIdx.x * 64 + wv * 16;
    if (node0 >= N) return;

    int arow = node0 + r15;
    if (arow >= N) arow = N - 1;
    bf16x8 bfr[4];
#pragma unroll
    for (int ks = 0; ks < 4; ks++)
        bfr[ks] = __builtin_nontemporal_load(
            (const bf16x8*)(Hin + (size_t)arow * 128 + kg * 8 + ks * 32));

    f32x4 acc[4];
#pragma unroll
    for (int c = 0; c < 4; c++) acc[c] = (f32x4){0.f, 0.f, 0.f, 0.f};

#pragma unroll
    for (int c = 0; c < 4; c++) {
        const unsigned short* wrow = Wt + (size_t)(c * 16 + r15) * 128 + kg * 8;
#pragma unroll
        for (int ks = 0; ks < 4; ks++) {
            bf16x8 afr = *(const bf16x8*)(wrow + ks * 32);
            acc[c] = __builtin_amdgcn_mfma_f32_16x16x32_bf16(afr, bfr[ks], acc[c], 0, 0, 0);
        }
    }
    const int node = node0 + r15;
    if (node < N) {
#pragma unroll
        for (int c = 0; c < 4; c++) {
            int col = c * 16 + kg * 4;
            *(uint2*)(g + (size_t)node * 64 + col) =
                make_uint2(pk2(acc[c][0], acc[c][1]), pk2(acc[c][2], acc[c][3]));
        }
    }
}

// ---------------- fused last: gather g (64-wide) + per-graph segment sums ----------------
__global__ __launch_bounds__(256) void fused_last2(
    const unsigned short* __restrict__ g,
    const int* __restrict__ rs, const int2* __restrict__ cw,
    const float* __restrict__ dinv, const int* __restrict__ batch,
    float* __restrict__ gsum /* [NSLOT][8][64] */, int N)
{
    __shared__ __align__(16) float R[64][68];
    __shared__ int gid[64];
    const int t = threadIdx.x;
    const int q = t & 7;         // 8 lanes per node (64 feats, 8 each)
    const int gi = t >> 3;       // 0..31
    const int nA = blockIdx.x * 64 + gi;
    const int nB = nA + 32;
    const bool vA = nA < N, vB = nB < N;

    float accA[8] = {0,0,0,0,0,0,0,0}, accB[8] = {0,0,0,0,0,0,0,0};
    if (vA) {
        float dA = dinv[nA];
        seed8(accA, dA * dA, *(const uint4*)(g + (size_t)nA * 64 + q * 8));
    }
    if (vB) {
        float dB = dinv[nB];
        seed8(accB, dB * dB, *(const uint4*)(g + (size_t)nB * 64 + q * 8));
    }
    int kA = 0, eA = 0, kB = 0, eB = 0;
    if (vA) { kA = rs[nA]; eA = rs[nA + 1]; }
    if (vB) { kB = rs[nB]; eB = rs[nB + 1]; }

    while (kA < eA || kB < eB) {
        int2 cA0 = (kA     < eA) ? cw[kA]     : make_int2(0, 0);
        int2 cA1 = (kA + 1 < eA) ? cw[kA + 1] : make_int2(0, 0);
        int2 cA2 = (kA + 2 < eA) ? cw[kA + 2] : make_int2(0, 0);
        int2 cA3 = (kA + 3 < eA) ? cw[kA + 3] : make_int2(0, 0);
        int2 cB0 = (kB     < eB) ? cw[kB]     : make_int2(0, 0);
        int2 cB1 = (kB + 1 < eB) ? cw[kB + 1] : make_int2(0, 0);
        int2 cB2 = (kB + 2 < eB) ? cw[kB + 2] : make_int2(0, 0);
        int2 cB3 = (kB + 3 < eB) ? cw[kB + 3] : make_int2(0, 0);
        uint4 vA0 = *(const uint4*)(g + (size_t)cA0.x * 64 + q * 8);
        uint4 vA1 = *(const uint4*)(g + (size_t)cA1.x * 64 + q * 8);
        uint4 vA2 = *(const uint4*)(g + (size_t)cA2.x * 64 + q * 8);
        uint4 vA3 = *(const uint4*)(g + (size_t)cA3.x * 64 + q * 8);
        uint4 vB0 = *(const uint4*)(g + (size_t)cB0.x * 64 + q * 8);
        uint4 vB1 = *(const uint4*)(g + (size_t)cB1.x * 64 + q * 8);
        uint4 vB2 = *(const uint4*)(g + (size_t)cB2.x * 64 + q * 8);
        uint4 vB3 = *(const uint4*)(g + (size_t)cB3.x * 64 + q * 8);
        fma8(accA, __int_as_float(cA0.y), vA0);
        fma8(accA, __int_as_float(cA1.y), vA1);
        fma8(accA, __int_as_float(cA2.y), vA2);
        fma8(accA, __int_as_float(cA3.y), vA3);
        fma8(accB, __int_as_float(cB0.y), vB0);
        fma8(accB, __int_as_float(cB1.y), vB1);
        fma8(accB, __int_as_float(cB2.y), vB2);
        fma8(accB, __int_as_float(cB3.y), vB3);
        kA += 4; kB += 4;
    }

#pragma unroll
    for (int j = 0; j < 8; j += 4) {
        *(float4*)&R[gi][q * 8 + j]      = make_float4(accA[j], accA[j+1], accA[j+2], accA[j+3]);
        *(float4*)&R[gi + 32][q * 8 + j] = make_float4(accB[j], accB[j+1], accB[j+2], accB[j+3]);
    }
    if (q == 0) {
        gid[gi]      = vA ? batch[nA] : -1;
        gid[gi + 32] = vB ? batch[nB] : -1;
    }
    __syncthreads();

    // segment-sum: quarter scans 16 rows for feat f
    const int f = t & 63;
    const int half = t >> 6;     // 0..3
    const int slot = blockIdx.x & (NSLOT - 1);
    float acc = 0.f;
    int cur = -1;
    for (int r = 0; r < 16; r++) {
        int row = half * 16 + r;
        int gg = gid[row];
        if (gg != cur) {
            if (cur >= 0) atomicAdd(&gsum[(size_t)(slot * 8 + cur) * 64 + f], acc);
            acc = 0.f; cur = gg;
        }
        if (gg >= 0) acc += R[row][f];
    }
    if (cur >= 0) atomicAdd(&gsum[(size_t)(slot * 8 + cur) * 64 + f], acc);
}

// ---------------- graph boundaries + final mean/bias/sigmoid ----------------
__global__ void gbound_k(const int* __restrict__ batch, int* __restrict__ gstart, int N, int G) {
    int i = blockIdx.x * 256 + threadIdx.x;
    if (i >= N) return;
    int b = batch[i];
    int prev = (i == 0) ? -1 : batch[i - 1];
    for (int g = prev + 1; g <= b; g++) gstart[g] = i;
    if (i == N - 1) for (int g = b + 1; g <= G; g++) gstart[g] = N;
}

__global__ void final4_k(const float* __restrict__ gsum, const int* __restrict__ gstart,
                         const float* __restrict__ b_out, float* __restrict__ out) {
    int t = threadIdx.x;          // 512 = 8 graphs * 64 feats
    int g = t >> 6, f = t & 63;
    float s = 0.f;
    for (int sl = 0; sl < NSLOT; sl++) s += gsum[(size_t)(sl * 8 + g) * 64 + f];
    int c = gstart[g + 1] - gstart[g];
    float v = s / (float)max(c, 1) + b_out[f];
    out[g * 64 + f] = 1.f / (1.f + expf(-v));
}

// ---------------- launch ----------------
extern "C" void kernel_launch(void* const* d_in, const int* in_sizes, int n_in,
                              void* d_out, int out_size, void* d_ws, size_t ws_size,
                              hipStream_t stream) {
    const float* x     = (const float*)d_in[0];
    const int*   ei    = (const int*)d_in[1];
    const int*   batch = (const int*)d_in[2];
    const float* W_in  = (const float*)d_in[3];
    const float* b_in  = (const float*)d_in[4];
    const float* W_h   = (const float*)d_in[5];
    const float* b_h   = (const float*)d_in[6];
    const float* W_out = (const float*)d_in[7];
    const float* b_out = (const float*)d_in[8];

    const int N = in_sizes[2];
    const int E = in_sizes[1] / 2;
    const int L = in_sizes[5] / (INTER * INTER);
    const int G = 8;
    const int* src = ei;
    const int* dst = ei + E;

    char* ws = (char*)d_ws;
    size_t off = 0;
    auto alloc = [&](size_t bytes) -> void* {
        void* p = ws + off;
        off += (bytes + 255) & ~(size_t)255;
        return p;
    };
    int*   cnt    = (int*)alloc((size_t)N * 4);
    int*   cursor = (int*)alloc((size_t)N * 4);
    int*   rs     = (int*)alloc((size_t)(N + 1) * 4);
    int*   bsums  = (int*)alloc(4096);
    float* dinv   = (float*)alloc((size_t)N * 4);
    int2*  cw     = (int2*)alloc((size_t)E * 8);
    float* ax     = (float*)alloc((size_t)N * 2 * 4);
    unsigned short* h   = (unsigned short*)alloc((size_t)N * INTER * 2);
    unsigned short* h2  = (unsigned short*)alloc((size_t)N * INTER * 2);
    unsigned short* g   = (unsigned short*)alloc((size_t)N * OUTD * 2);
    unsigned short* Wht = (unsigned short*)alloc((size_t)L * INTER * INTER * 2);
    unsigned short* Wot = (unsigned short*)alloc((size_t)OUTD * INTER * 2);
    float* gsum   = (float*)alloc((size_t)NSLOT * 8 * OUTD * 4);
    int*   gstart = (int*)alloc((G + 1) * 4);
    int*   hist   = (int*)alloc(NBIN * 4);
    int*   bincur = (int*)alloc(NBIN * 4);
    int*   order  = (int*)alloc((size_t)N * 4);
    (void)ws_size; (void)n_in;

    hipMemsetAsync(cnt, 0, (size_t)N * 4, stream);
    hipMemsetAsync(cursor, 0, (size_t)N * 4, stream);
    hipMemsetAsync(gsum, 0, (size_t)NSLOT * 8 * OUTD * 4, stream);
    hipMemsetAsync(hist, 0, NBIN * 4, stream);

    // CSR build
    count_k<<<(E + 255) / 256, 256, 0, stream>>>(dst, cnt, E);
    dinv_k<<<(N + 255) / 256, 256, 0, stream>>>(cnt, dinv, N);
    int nsb = (N + SCAN_E - 1) / SCAN_E;
    scan_block<<<nsb, SCAN_T, 0, stream>>>(cnt, rs, bsums, N);
    scan_block<<<1, SCAN_T, 0, stream>>>(bsums, bsums, nullptr, nsb);
    scan_add<<<nsb, SCAN_T, 0, stream>>>(rs, bsums, N, E);
    scatter_k<<<(E + 255) / 256, 256, 0, stream>>>(src, dst, rs, cursor, dinv, cw, E);
    gbound_k<<<(N + 255) / 256, 256, 0, stream>>>(batch, gstart, N, G);

    // degree counting sort -> order[]
    dhist_k<<<(N + 255) / 256, 256, 0, stream>>>(cnt, hist, N);
    dscan_k<<<1, 64, 0, stream>>>(hist, bincur);
    dorder_k<<<(N + 255) / 256, 256, 0, stream>>>(cnt, bincur, order, N);

    // weight prep
    wprep_h<<<(L * INTER * INTER + 255) / 256, 256, 0, stream>>>(W_h, Wht, L);
    wprep_o<<<(OUTD * INTER + 255) / 256, 256, 0, stream>>>(W_out, Wot);

    // input layer
    agg2<<<(N + 255) / 256, 256, 0, stream>>>(x, rs, cw, dinv, ax, N);
    gemm_in<<<(N + 1) / 2, 256, 0, stream>>>(ax, W_in, b_in, h, N);

    // hidden layers (fused gather + MFMA transform), ping-pong h <-> h2
    unsigned short* hin = h;
    unsigned short* hout = h2;
    for (int l = 0; l < L; l++) {
        fused_hidden4<<<(N + 31) / 32, 256, 0, stream>>>(
            hin, rs, cw, dinv, order, Wht + (size_t)l * INTER * INTER, b_h + (size_t)l * INTER, hout, N);
        unsigned short* tmp = hin; hin = hout; hout = tmp;
    }

    // output layer: transform-first (halves gather width), then gather + pool
    gemm_out<<<(N + 63) / 64, 256, 0, stream>>>(hin, Wot, g, N);
    fused_last2<<<(N + 63) / 64, 256, 0, stream>>>(g, rs, cw, dinv, batch, gsum, N);
    final4_k<<<1, 512, 0, stream>>>(gsum, gstart, b_out, (float*)d_out);
}

// Round 10
// 542.875 us; speedup vs baseline: 4.0047x; 4.0047x over previous
//
#include <hip/hip_runtime.h>
#include <math.h>

// ---------------- constants ----------------
#define INTER 128
#define OUTD  64
#define SCAN_T 256
#define SCAN_E 1024
#define NSLOT 64     // graph-sum contention-spreading slots
#define NBIN  128    // degree bins for counting sort

using bf16x8 = __attribute__((ext_vector_type(8))) short;
using f32x4  = __attribute__((ext_vector_type(4))) float;

static __device__ __forceinline__ unsigned short f2bf(float f) {
    unsigned int u = __float_as_uint(f);
    u += 0x7fffu + ((u >> 16) & 1u);          // RTNE
    return (unsigned short)(u >> 16);
}
static __device__ __forceinline__ unsigned int pk2(float a, float b) {
    return (unsigned int)f2bf(a) | ((unsigned int)f2bf(b) << 16);
}
static __device__ __forceinline__ float bflo(unsigned int u) { return __uint_as_float(u << 16); }
static __device__ __forceinline__ float bfhi(unsigned int u) { return __uint_as_float(u & 0xffff0000u); }

static __device__ __forceinline__ void fma8(float* a, float w, uint4 v) {
    a[0] = fmaf(w, bflo(v.x), a[0]); a[1] = fmaf(w, bfhi(v.x), a[1]);
    a[2] = fmaf(w, bflo(v.y), a[2]); a[3] = fmaf(w, bfhi(v.y), a[3]);
    a[4] = fmaf(w, bflo(v.z), a[4]); a[5] = fmaf(w, bfhi(v.z), a[5]);
    a[6] = fmaf(w, bflo(v.w), a[6]); a[7] = fmaf(w, bfhi(v.w), a[7]);
}
static __device__ __forceinline__ void seed8(float* a, float sn, uint4 v) {
    a[0] = sn * bflo(v.x); a[1] = sn * bfhi(v.x);
    a[2] = sn * bflo(v.y); a[3] = sn * bfhi(v.y);
    a[4] = sn * bflo(v.z); a[5] = sn * bfhi(v.z);
    a[6] = sn * bflo(v.w); a[7] = sn * bfhi(v.w);
}

// ---------------- CSR build ----------------
__global__ void count_k(const int* __restrict__ dst, int* __restrict__ cnt, int E) {
    int e = blockIdx.x * 256 + threadIdx.x;
    if (e < E) atomicAdd(&cnt[dst[e]], 1);
}

__global__ void dinv_k(const int* __restrict__ cnt, float* __restrict__ dinv, int N) {
    int i = blockIdx.x * 256 + threadIdx.x;
    if (i < N) dinv[i] = rsqrtf((float)(cnt[i] + 1));
}

__global__ void scan_block(const int* __restrict__ in, int* __restrict__ out,
                           int* __restrict__ bsums, int n) {
    __shared__ int sh[SCAN_T];
    int base = blockIdx.x * SCAN_E;
    int t = threadIdx.x;
    int v[4];
    int s = 0;
#pragma unroll
    for (int i = 0; i < 4; i++) {
        int idx = base + t * 4 + i;
        v[i] = (idx < n) ? in[idx] : 0;
        s += v[i];
    }
    sh[t] = s;
    __syncthreads();
    for (int off = 1; off < SCAN_T; off <<= 1) {
        int x = (t >= off) ? sh[t - off] : 0;
        __syncthreads();
        sh[t] += x;
        __syncthreads();
    }
    int excl = (t == 0) ? 0 : sh[t - 1];
    if (bsums && t == SCAN_T - 1) bsums[blockIdx.x] = sh[t];
#pragma unroll
    for (int i = 0; i < 4; i++) {
        int idx = base + t * 4 + i;
        if (idx < n) out[idx] = excl;
        excl += v[i];
    }
}

__global__ void scan_add(int* __restrict__ out, const int* __restrict__ bsums, int n, int total) {
    int idx = blockIdx.x * SCAN_E + threadIdx.x * 4;
    int add = bsums[blockIdx.x];
#pragma unroll
    for (int i = 0; i < 4; i++) {
        int j = idx + i;
        if (j < n) out[j] += add;
    }
    if (blockIdx.x == 0 && threadIdx.x == 0) out[n] = total;
}

__global__ void scatter_k(const int* __restrict__ src, const int* __restrict__ dst,
                          const int* __restrict__ rs, int* __restrict__ cursor,
                          const float* __restrict__ dinv,
                          int2* __restrict__ cw, int E) {
    int e = blockIdx.x * 256 + threadIdx.x;
    if (e >= E) return;
    int s = src[e], d = dst[e];
    int pos = rs[d] + atomicAdd(&cursor[d], 1);
    cw[pos] = make_int2(s, __float_as_int(dinv[s] * dinv[d]));
}

// ---------------- degree counting sort (contention-free, no global atomics) ----
// 1) per-block LDS histogram -> blockhist[bin * nblk + blk]  (bin-major)
__global__ __launch_bounds__(256) void dhist2_k(const int* __restrict__ cnt,
                                                int* __restrict__ blockhist,
                                                int N, int nblk) {
    __shared__ int hist[NBIN];
    int t = threadIdx.x;
    if (t < NBIN) hist[t] = 0;
    __syncthreads();
    int i = blockIdx.x * 256 + t;
    if (i < N) atomicAdd(&hist[min(cnt[i], NBIN - 1)], 1);
    __syncthreads();
    if (t < NBIN) blockhist[t * nblk + blockIdx.x] = hist[t];
}

// 2) global exclusive scan of blockhist (reuses scan_block/scan_add) -> offs
// 3) scatter nodes: rank within (bin, block) via LDS cursor
__global__ __launch_bounds__(256) void dorder2_k(const int* __restrict__ cnt,
                                                 const int* __restrict__ offs,
                                                 int* __restrict__ order,
                                                 int N, int nblk) {
    __shared__ int cur[NBIN];
    int t = threadIdx.x;
    if (t < NBIN) cur[t] = 0;
    __syncthreads();
    int i = blockIdx.x * 256 + t;
    if (i >= N) return;
    int d = min(cnt[i], NBIN - 1);
    int r = atomicAdd(&cur[d], 1);              // LDS atomic, block-local
    order[offs[d * nblk + blockIdx.x] + r] = i;
}

// ---------------- weight prep (fp32 -> bf16, transposed [n][k]) ----------------
__global__ void wprep_h(const float* __restrict__ W, unsigned short* __restrict__ Wt, int L) {
    int tid = blockIdx.x * 256 + threadIdx.x;
    if (tid >= L * INTER * INTER) return;
    int l = tid / (INTER * INTER);
    int r = tid % (INTER * INTER);
    int n = r / INTER, k = r % INTER;
    Wt[tid] = f2bf(W[(size_t)l * INTER * INTER + (size_t)k * INTER + n]);
}

__global__ void wprep_o(const float* __restrict__ W, unsigned short* __restrict__ Wt) {
    int tid = blockIdx.x * 256 + threadIdx.x;
    if (tid >= OUTD * INTER) return;
    int n = tid / INTER, k = tid % INTER;
    Wt[tid] = f2bf(W[(size_t)k * OUTD + n]);
}

// ---------------- input layer ----------------
__global__ void agg2(const float* __restrict__ x, const int* __restrict__ rs,
                     const int2* __restrict__ cw, const float* __restrict__ dinv,
                     float* __restrict__ ax, int N) {
    int i = blockIdx.x * 256 + threadIdx.x;
    if (i >= N) return;
    float di = dinv[i];
    float sn = di * di;
    float2 xv = ((const float2*)x)[i];
    float a0 = sn * xv.x, a1 = sn * xv.y;
    int e0 = rs[i], e1 = rs[i + 1];
    for (int k = e0; k < e1; k++) {
        int2 c = cw[k];
        float wk = __int_as_float(c.y);
        float2 xs = ((const float2*)x)[c.x];
        a0 += wk * xs.x;
        a1 += wk * xs.y;
    }
    ((float2*)ax)[i] = make_float2(a0, a1);
}

// h = ax (N x 2) @ W_in (2 x 128) + b_in  -> bf16
__global__ void gemm_in(const float* __restrict__ ax, const float* __restrict__ Wi,
                        const float* __restrict__ bi, unsigned short* __restrict__ h, int N) {
    int node = blockIdx.x * 2 + threadIdx.x / 128;
    int j = threadIdx.x % 128;
    if (node >= N) return;
    float2 a = ((const float2*)ax)[node];
    h[(size_t)node * 128 + j] = f2bf(fmaf(a.x, Wi[j], fmaf(a.y, Wi[128 + j], bi[j])));
}

// ---------------- fused hidden layer: Hout = relu((A_hat Hin) W + b) ----------------
// Nodes processed in degree-sorted order (order[]), so each block's 32 nodes have
// ~equal degree -> minimal serialization at the block barrier.
__global__ __launch_bounds__(256) void fused_hidden4(
    const unsigned short* __restrict__ Hin,
    const int* __restrict__ rs, const int2* __restrict__ cw,
    const float* __restrict__ dinv, const int* __restrict__ order,
    const unsigned short* __restrict__ Wt,   // [128][128] bf16, Wt[n][k] = W[k][n]
    const float* __restrict__ bias,
    unsigned short* __restrict__ Hout, int N)
{
    __shared__ __align__(16) unsigned short T[32][136];
    __shared__ int nodeid[32];
    const int t = threadIdx.x;
    const int q = t & 15;        // 16 lanes per node
    const int gi = t >> 4;       // 0..15
    const int sA = blockIdx.x * 32 + gi;
    const int sB = sA + 16;
    const bool vA = sA < N, vB = sB < N;
    const int nA = vA ? order[sA] : 0;
    const int nB = vB ? order[sB] : 0;
    if (q == 0) {
        nodeid[gi]      = vA ? nA : -1;
        nodeid[gi + 16] = vB ? nB : -1;
    }

    float accA[8] = {0,0,0,0,0,0,0,0}, accB[8] = {0,0,0,0,0,0,0,0};
    if (vA) {
        float dA = dinv[nA];
        seed8(accA, dA * dA, *(const uint4*)(Hin + (size_t)nA * 128 + q * 8));
    }
    if (vB) {
        float dB = dinv[nB];
        seed8(accB, dB * dB, *(const uint4*)(Hin + (size_t)nB * 128 + q * 8));
    }
    int kA = 0, eA = 0, kB = 0, eB = 0;
    if (vA) { kA = rs[nA]; eA = rs[nA + 1]; }
    if (vB) { kB = rs[nB]; eB = rs[nB + 1]; }

    while (kA < eA || kB < eB) {
        int2 cA0 = (kA     < eA) ? cw[kA]     : make_int2(0, 0);
        int2 cA1 = (kA + 1 < eA) ? cw[kA + 1] : make_int2(0, 0);
        int2 cA2 = (kA + 2 < eA) ? cw[kA + 2] : make_int2(0, 0);
        int2 cA3 = (kA + 3 < eA) ? cw[kA + 3] : make_int2(0, 0);
        int2 cB0 = (kB     < eB) ? cw[kB]     : make_int2(0, 0);
        int2 cB1 = (kB + 1 < eB) ? cw[kB + 1] : make_int2(0, 0);
        int2 cB2 = (kB + 2 < eB) ? cw[kB + 2] : make_int2(0, 0);
        int2 cB3 = (kB + 3 < eB) ? cw[kB + 3] : make_int2(0, 0);
        uint4 vA0 = *(const uint4*)(Hin + (size_t)cA0.x * 128 + q * 8);
        uint4 vA1 = *(const uint4*)(Hin + (size_t)cA1.x * 128 + q * 8);
        uint4 vA2 = *(const uint4*)(Hin + (size_t)cA2.x * 128 + q * 8);
        uint4 vA3 = *(const uint4*)(Hin + (size_t)cA3.x * 128 + q * 8);
        uint4 vB0 = *(const uint4*)(Hin + (size_t)cB0.x * 128 + q * 8);
        uint4 vB1 = *(const uint4*)(Hin + (size_t)cB1.x * 128 + q * 8);
        uint4 vB2 = *(const uint4*)(Hin + (size_t)cB2.x * 128 + q * 8);
        uint4 vB3 = *(const uint4*)(Hin + (size_t)cB3.x * 128 + q * 8);
        fma8(accA, __int_as_float(cA0.y), vA0);
        fma8(accA, __int_as_float(cA1.y), vA1);
        fma8(accA, __int_as_float(cA2.y), vA2);
        fma8(accA, __int_as_float(cA3.y), vA3);
        fma8(accB, __int_as_float(cB0.y), vB0);
        fma8(accB, __int_as_float(cB1.y), vB1);
        fma8(accB, __int_as_float(cB2.y), vB2);
        fma8(accB, __int_as_float(cB3.y), vB3);
        kA += 4; kB += 4;
    }

    {
        uint4 oA = make_uint4(pk2(accA[0], accA[1]), pk2(accA[2], accA[3]),
                              pk2(accA[4], accA[5]), pk2(accA[6], accA[7]));
        uint4 oB = make_uint4(pk2(accB[0], accB[1]), pk2(accB[2], accB[3]),
                              pk2(accB[4], accB[5]), pk2(accB[6], accB[7]));
        *(uint4*)&T[gi][q * 8] = oA;
        *(uint4*)&T[gi + 16][q * 8] = oB;
    }
    __syncthreads();

    // phase 2
    const int wv = t >> 6;       // wave -> col slice [wv*32, wv*32+32)
    const int lane = t & 63;
    const int r15 = lane & 15;
    const int kg = lane >> 4;

    bf16x8 bfr[2][4];
#pragma unroll
    for (int nc = 0; nc < 2; nc++)
#pragma unroll
        for (int ks = 0; ks < 4; ks++)
            bfr[nc][ks] = *(const bf16x8*)&T[nc * 16 + r15][kg * 8 + ks * 32];

    f32x4 acc[2][2];
#pragma unroll
    for (int nc = 0; nc < 2; nc++)
#pragma unroll
        for (int c = 0; c < 2; c++) acc[nc][c] = (f32x4){0.f, 0.f, 0.f, 0.f};

#pragma unroll
    for (int c = 0; c < 2; c++) {
        const unsigned short* wrow = Wt + (size_t)(wv * 32 + c * 16 + r15) * 128 + kg * 8;
#pragma unroll
        for (int ks = 0; ks < 4; ks++) {
            bf16x8 afr = *(const bf16x8*)(wrow + ks * 32);
            acc[0][c] = __builtin_amdgcn_mfma_f32_16x16x32_bf16(afr, bfr[0][ks], acc[0][c], 0, 0, 0);
            acc[1][c] = __builtin_amdgcn_mfma_f32_16x16x32_bf16(afr, bfr[1][ks], acc[1][c], 0, 0, 0);
        }
    }

#pragma unroll
    for (int nc = 0; nc < 2; nc++) {
        const int node = nodeid[nc * 16 + r15];
        if (node >= 0) {
#pragma unroll
            for (int c = 0; c < 2; c++) {
                int col = wv * 32 + c * 16 + kg * 4;
                float4 bv = *(const float4*)(bias + col);
                float v0 = fmaxf(acc[nc][c][0] + bv.x, 0.f);
                float v1 = fmaxf(acc[nc][c][1] + bv.y, 0.f);
                float v2 = fmaxf(acc[nc][c][2] + bv.z, 0.f);
                float v3 = fmaxf(acc[nc][c][3] + bv.w, 0.f);
                *(uint2*)(Hout + (size_t)node * 128 + col) = make_uint2(pk2(v0, v1), pk2(v2, v3));
            }
        }
    }
}

// ---------------- output transform: g = Hin (N x 128) @ W_out (128 x 64) -> bf16 ----------------
__global__ __launch_bounds__(256) void gemm_out(const unsigned short* __restrict__ Hin,
                                                const unsigned short* __restrict__ Wt, // [64][128]
                                                unsigned short* __restrict__ g, int N) {
    const int wv = threadIdx.x >> 6;
    const int lane = threadIdx.x & 63;
    const int r15 = lane & 15;
    const int kg = lane >> 4;
    const int node0 = blockIdx.x * 64 + wv * 16;
    if (node0 >= N) return;

    int arow = node0 + r15;
    if (arow >= N) arow = N - 1;
    bf16x8 bfr[4];
#pragma unroll
    for (int ks = 0; ks < 4; ks++)
        bfr[ks] = __builtin_nontemporal_load(
            (const bf16x8*)(Hin + (size_t)arow * 128 + kg * 8 + ks * 32));

    f32x4 acc[4];
#pragma unroll
    for (int c = 0; c < 4; c++) acc[c] = (f32x4){0.f, 0.f, 0.f, 0.f};

#pragma unroll
    for (int c = 0; c < 4; c++) {
        const unsigned short* wrow = Wt + (size_t)(c * 16 + r15) * 128 + kg * 8;
#pragma unroll
        for (int ks = 0; ks < 4; ks++) {
            bf16x8 afr = *(const bf16x8*)(wrow + ks * 32);
            acc[c] = __builtin_amdgcn_mfma_f32_16x16x32_bf16(afr, bfr[ks], acc[c], 0, 0, 0);
        }
    }
    const int node = node0 + r15;
    if (node < N) {
#pragma unroll
        for (int c = 0; c < 4; c++) {
            int col = c * 16 + kg * 4;
            *(uint2*)(g + (size_t)node * 64 + col) =
                make_uint2(pk2(acc[c][0], acc[c][1]), pk2(acc[c][2], acc[c][3]));
        }
    }
}

// ---------------- fused last: gather g (64-wide) + per-graph segment sums ----------------
__global__ __launch_bounds__(256) void fused_last2(
    const unsigned short* __restrict__ g,
    const int* __restrict__ rs, const int2* __restrict__ cw,
    const float* __restrict__ dinv, const int* __restrict__ batch,
    float* __restrict__ gsum /* [NSLOT][8][64] */, int N)
{
    __shared__ __align__(16) float R[64][68];
    __shared__ int gid[64];
    const int t = threadIdx.x;
    const int q = t & 7;         // 8 lanes per node (64 feats, 8 each)
    const int gi = t >> 3;       // 0..31
    const int nA = blockIdx.x * 64 + gi;
    const int nB = nA + 32;
    const bool vA = nA < N, vB = nB < N;

    float accA[8] = {0,0,0,0,0,0,0,0}, accB[8] = {0,0,0,0,0,0,0,0};
    if (vA) {
        float dA = dinv[nA];
        seed8(accA, dA * dA, *(const uint4*)(g + (size_t)nA * 64 + q * 8));
    }
    if (vB) {
        float dB = dinv[nB];
        seed8(accB, dB * dB, *(const uint4*)(g + (size_t)nB * 64 + q * 8));
    }
    int kA = 0, eA = 0, kB = 0, eB = 0;
    if (vA) { kA = rs[nA]; eA = rs[nA + 1]; }
    if (vB) { kB = rs[nB]; eB = rs[nB + 1]; }

    while (kA < eA || kB < eB) {
        int2 cA0 = (kA     < eA) ? cw[kA]     : make_int2(0, 0);
        int2 cA1 = (kA + 1 < eA) ? cw[kA + 1] : make_int2(0, 0);
        int2 cA2 = (kA + 2 < eA) ? cw[kA + 2] : make_int2(0, 0);
        int2 cA3 = (kA + 3 < eA) ? cw[kA + 3] : make_int2(0, 0);
        int2 cB0 = (kB     < eB) ? cw[kB]     : make_int2(0, 0);
        int2 cB1 = (kB + 1 < eB) ? cw[kB + 1] : make_int2(0, 0);
        int2 cB2 = (kB + 2 < eB) ? cw[kB + 2] : make_int2(0, 0);
        int2 cB3 = (kB + 3 < eB) ? cw[kB + 3] : make_int2(0, 0);
        uint4 vA0 = *(const uint4*)(g + (size_t)cA0.x * 64 + q * 8);
        uint4 vA1 = *(const uint4*)(g + (size_t)cA1.x * 64 + q * 8);
        uint4 vA2 = *(const uint4*)(g + (size_t)cA2.x * 64 + q * 8);
        uint4 vA3 = *(const uint4*)(g + (size_t)cA3.x * 64 + q * 8);
        uint4 vB0 = *(const uint4*)(g + (size_t)cB0.x * 64 + q * 8);
        uint4 vB1 = *(const uint4*)(g + (size_t)cB1.x * 64 + q * 8);
        uint4 vB2 = *(const uint4*)(g + (size_t)cB2.x * 64 + q * 8);
        uint4 vB3 = *(const uint4*)(g + (size_t)cB3.x * 64 + q * 8);
        fma8(accA, __int_as_float(cA0.y), vA0);
        fma8(accA, __int_as_float(cA1.y), vA1);
        fma8(accA, __int_as_float(cA2.y), vA2);
        fma8(accA, __int_as_float(cA3.y), vA3);
        fma8(accB, __int_as_float(cB0.y), vB0);
        fma8(accB, __int_as_float(cB1.y), vB1);
        fma8(accB, __int_as_float(cB2.y), vB2);
        fma8(accB, __int_as_float(cB3.y), vB3);
        kA += 4; kB += 4;
    }

#pragma unroll
    for (int j = 0; j < 8; j += 4) {
        *(float4*)&R[gi][q * 8 + j]      = make_float4(accA[j], accA[j+1], accA[j+2], accA[j+3]);
        *(float4*)&R[gi + 32][q * 8 + j] = make_float4(accB[j], accB[j+1], accB[j+2], accB[j+3]);
    }
    if (q == 0) {
        gid[gi]      = vA ? batch[nA] : -1;
        gid[gi + 32] = vB ? batch[nB] : -1;
    }
    __syncthreads();

    // segment-sum: quarter scans 16 rows for feat f
    const int f = t & 63;
    const int half = t >> 6;     // 0..3
    const int slot = blockIdx.x & (NSLOT - 1);
    float acc = 0.f;
    int cur = -1;
    for (int r = 0; r < 16; r++) {
        int row = half * 16 + r;
        int gg = gid[row];
        if (gg != cur) {
            if (cur >= 0) atomicAdd(&gsum[(size_t)(slot * 8 + cur) * 64 + f], acc);
            acc = 0.f; cur = gg;
        }
        if (gg >= 0) acc += R[row][f];
    }
    if (cur >= 0) atomicAdd(&gsum[(size_t)(slot * 8 + cur) * 64 + f], acc);
}

// ---------------- graph boundaries + final mean/bias/sigmoid ----------------
__global__ void gbound_k(const int* __restrict__ batch, int* __restrict__ gstart, int N, int G) {
    int i = blockIdx.x * 256 + threadIdx.x;
    if (i >= N) return;
    int b = batch[i];
    int prev = (i == 0) ? -1 : batch[i - 1];
    for (int g = prev + 1; g <= b; g++) gstart[g] = i;
    if (i == N - 1) for (int g = b + 1; g <= G; g++) gstart[g] = N;
}

__global__ void final4_k(const float* __restrict__ gsum, const int* __restrict__ gstart,
                         const float* __restrict__ b_out, float* __restrict__ out) {
    int t = threadIdx.x;          // 512 = 8 graphs * 64 feats
    int g = t >> 6, f = t & 63;
    float s = 0.f;
    for (int sl = 0; sl < NSLOT; sl++) s += gsum[(size_t)(sl * 8 + g) * 64 + f];
    int c = gstart[g + 1] - gstart[g];
    float v = s / (float)max(c, 1) + b_out[f];
    out[g * 64 + f] = 1.f / (1.f + expf(-v));
}

// ---------------- launch ----------------
extern "C" void kernel_launch(void* const* d_in, const int* in_sizes, int n_in,
                              void* d_out, int out_size, void* d_ws, size_t ws_size,
                              hipStream_t stream) {
    const float* x     = (const float*)d_in[0];
    const int*   ei    = (const int*)d_in[1];
    const int*   batch = (const int*)d_in[2];
    const float* W_in  = (const float*)d_in[3];
    const float* b_in  = (const float*)d_in[4];
    const float* W_h   = (const float*)d_in[5];
    const float* b_h   = (const float*)d_in[6];
    const float* W_out = (const float*)d_in[7];
    const float* b_out = (const float*)d_in[8];

    const int N = in_sizes[2];
    const int E = in_sizes[1] / 2;
    const int L = in_sizes[5] / (INTER * INTER);
    const int G = 8;
    const int* src = ei;
    const int* dst = ei + E;
    const int nblk = (N + 255) / 256;
    const int nbh = NBIN * nblk;              // blockhist size

    char* ws = (char*)d_ws;
    size_t off = 0;
    auto alloc = [&](size_t bytes) -> void* {
        void* p = ws + off;
        off += (bytes + 255) & ~(size_t)255;
        return p;
    };
    int*   cnt    = (int*)alloc((size_t)N * 4);
    int*   cursor = (int*)alloc((size_t)N * 4);
    int*   rs     = (int*)alloc((size_t)(N + 1) * 4);
    int*   bsums  = (int*)alloc(4096);
    float* dinv   = (float*)alloc((size_t)N * 4);
    int2*  cw     = (int2*)alloc((size_t)E * 8);
    float* ax     = (float*)alloc((size_t)N * 2 * 4);
    unsigned short* h   = (unsigned short*)alloc((size_t)N * INTER * 2);
    unsigned short* h2  = (unsigned short*)alloc((size_t)N * INTER * 2);
    unsigned short* g   = (unsigned short*)alloc((size_t)N * OUTD * 2);
    unsigned short* Wht = (unsigned short*)alloc((size_t)L * INTER * INTER * 2);
    unsigned short* Wot = (unsigned short*)alloc((size_t)OUTD * INTER * 2);
    float* gsum   = (float*)alloc((size_t)NSLOT * 8 * OUTD * 4);
    int*   gstart = (int*)alloc((G + 1) * 4);
    int*   bh     = (int*)alloc((size_t)(nbh + 1) * 4);   // blockhist -> offsets (scanned in place)
    int*   order  = (int*)alloc((size_t)N * 4);
    (void)ws_size; (void)n_in;

    hipMemsetAsync(cnt, 0, (size_t)N * 4, stream);
    hipMemsetAsync(cursor, 0, (size_t)N * 4, stream);
    hipMemsetAsync(gsum, 0, (size_t)NSLOT * 8 * OUTD * 4, stream);

    // CSR build
    count_k<<<(E + 255) / 256, 256, 0, stream>>>(dst, cnt, E);
    dinv_k<<<nblk, 256, 0, stream>>>(cnt, dinv, N);
    int nsb = (N + SCAN_E - 1) / SCAN_E;
    scan_block<<<nsb, SCAN_T, 0, stream>>>(cnt, rs, bsums, N);
    scan_block<<<1, SCAN_T, 0, stream>>>(bsums, bsums, nullptr, nsb);
    scan_add<<<nsb, SCAN_T, 0, stream>>>(rs, bsums, N, E);
    scatter_k<<<(E + 255) / 256, 256, 0, stream>>>(src, dst, rs, cursor, dinv, cw, E);
    gbound_k<<<nblk, 256, 0, stream>>>(batch, gstart, N, G);

    // degree counting sort (contention-free) -> order[]
    dhist2_k<<<nblk, 256, 0, stream>>>(cnt, bh, N, nblk);
    int nsb2 = (nbh + SCAN_E - 1) / SCAN_E;
    scan_block<<<nsb2, SCAN_T, 0, stream>>>(bh, bh, bsums, nbh);
    scan_block<<<1, SCAN_T, 0, stream>>>(bsums, bsums, nullptr, nsb2);
    scan_add<<<nsb2, SCAN_T, 0, stream>>>(bh, bsums, nbh, N);
    dorder2_k<<<nblk, 256, 0, stream>>>(cnt, bh, order, N, nblk);

    // weight prep
    wprep_h<<<(L * INTER * INTER + 255) / 256, 256, 0, stream>>>(W_h, Wht, L);
    wprep_o<<<(OUTD * INTER + 255) / 256, 256, 0, stream>>>(W_out, Wot);

    // input layer
    agg2<<<nblk, 256, 0, stream>>>(x, rs, cw, dinv, ax, N);
    gemm_in<<<(N + 1) / 2, 256, 0, stream>>>(ax, W_in, b_in, h, N);

    // hidden layers (fused gather + MFMA transform), ping-pong h <-> h2
    unsigned short* hin = h;
    unsigned short* hout = h2;
    for (int l = 0; l < L; l++) {
        fused_hidden4<<<(N + 31) / 32, 256, 0, stream>>>(
            hin, rs, cw, dinv, order, Wht + (size_t)l * INTER * INTER, b_h + (size_t)l * INTER, hout, N);
        unsigned short* tmp = hin; hin = hout; hout = tmp;
    }

    // output layer: transform-first (halves gather width), then gather + pool
    gemm_out<<<(N + 63) / 64, 256, 0, stream>>>(hin, Wot, g, N);
    fused_last2<<<(N + 63) / 64, 256, 0, stream>>>(g, rs, cw, dinv, batch, gsum, N);
    final4_k<<<1, 512, 0, stream>>>(gsum, gstart, b_out, (float*)d_out);
}